// Round 17
// baseline (40.774 us; speedup 1.0000x reference)
//
#include <hip/hip_runtime.h>
#include <math.h>

namespace {
constexpr int NV = 3;    // views
constexpr int NC = 16;   // channels
constexpr int ND = 32;   // depths
constexpr int NH = 256;
constexpr int NW = 320;
constexpr int HW = NH * NW;       // 81920
#define SYM(i, j) ((i) * 4 + (j) - (i) * ((i) + 1) / 2)
}

// rcp + 1 Newton step (same sequence everywhere -> consistent anchors).
__device__ __forceinline__ float frcp(float z) {
    float r = __builtin_amdgcn_rcpf(z);
    return r * fmaf(-z, r, 2.0f);
}

// ---------------------------------------------------------------------------
// R17 = R16 structure at 8 lanes/pixel (TLP x2: 10240 waves vs 5120 — the
// kernel was latency-bound at 5 waves/SIMD of total work with no refill).
//  - lane r (= tid&7): 2 channels (2r, 2r+1) in stats; 4 depths (4r..4r+3).
//  - 3-step butterfly allreduce (xor 1,2,4) of the 45 quad-form sums.
//  - basis change DROPPED (250 VALU duplicated/lane doesn't amortize over
//    4 depths): eval uses the quad-form directly (~100 VALU/depth), with
//    off-diagonal doubling post-allreduce (R9 semantics).
//  - early loads (dep0, 2 ref channels, 4 depth values) hoisted to the top
//    so their latency hides under the uniform proj math (R16 win).
//  - masks folded into gathered corner values (R13 win) -> fast-path weights
//    are pure bilinear; exact slow-path regather guards window deviation.
// ---------------------------------------------------------------------------
__global__ __launch_bounds__(256) void mega4_kernel(
    const float* __restrict__ feats,   // [V][C][HW]
    const float* __restrict__ pm,      // [V][2][4][4]
    const float* __restrict__ dvals,   // [D][HW]
    const float* __restrict__ wreg,    // [C]
    float* __restrict__ out)           // depth[HW] | conf[HW] | prob[D][HW]
{
    const unsigned tid = blockIdx.x * 256u + threadIdx.x;
    const unsigned n = tid >> 3;       // pixel
    const int r8 = (int)(tid & 7u);    // lane-in-group
    const int d0 = r8 * 4;
    const int y = (int)(n / NW);
    const int x = (int)(n - (unsigned)y * NW);
    const float fx = (float)x, fy = (float)y;
    const unsigned voff = n * 4u;

    const char* fb = (const char*)feats;
    const char* f1b = fb + (size_t)1 * NC * HW * 4;
    const char* f2b = fb + (size_t)2 * NC * HW * 4;

    // ------- EARLY LOADS (addresses known at thread start) -----------------
    const float dep0 = *(const float*)((const char*)dvals + voff);
    float rf[2];
#pragma unroll
    for (int c2 = 0; c2 < 2; ++c2)
        rf[c2] = *(const float*)(fb + (size_t)(r8 * 2 + c2) * HW * 4 + voff);
    float dv[4];
#pragma unroll
    for (int i = 0; i < 4; ++i)
        dv[i] = *(const float*)((const char*)dvals +
                                (size_t)(d0 + i) * HW * 4 + voff);

    // ---------------- phase 0: projection matrices (uniform math) ----------
    float P[NV][4][4];
#pragma unroll
    for (int v = 0; v < NV; ++v) {
        const float* E = pm + v * 2 * 16;
        const float* K = pm + v * 2 * 16 + 16;
#pragma unroll
        for (int j = 0; j < 4; ++j) P[v][3][j] = E[12 + j];
#pragma unroll
        for (int i = 0; i < 3; ++i)
#pragma unroll
            for (int j = 0; j < 4; ++j) {
                float acc = 0.f;
#pragma unroll
                for (int k = 0; k < 3; ++k) acc += K[i * 4 + k] * E[k * 4 + j];
                P[v][i][j] = acc;
            }
    }
    float Inv[4][4];
    {
        const float m00 = P[0][0][0], m01 = P[0][0][1], m02 = P[0][0][2], m03 = P[0][0][3];
        const float m10 = P[0][1][0], m11 = P[0][1][1], m12 = P[0][1][2], m13 = P[0][1][3];
        const float m20 = P[0][2][0], m21 = P[0][2][1], m22 = P[0][2][2], m23 = P[0][2][3];
        const float m30 = P[0][3][0], m31 = P[0][3][1], m32 = P[0][3][2], m33 = P[0][3][3];
        const float s0 = m00 * m11 - m10 * m01;
        const float s1 = m00 * m12 - m10 * m02;
        const float s2 = m00 * m13 - m10 * m03;
        const float s3 = m01 * m12 - m11 * m02;
        const float s4 = m01 * m13 - m11 * m03;
        const float s5 = m02 * m13 - m12 * m03;
        const float c5 = m22 * m33 - m32 * m23;
        const float c4_ = m21 * m33 - m31 * m23;
        const float c3 = m21 * m32 - m31 * m22;
        const float c2 = m20 * m33 - m30 * m23;
        const float c1 = m20 * m32 - m30 * m22;
        const float c0 = m20 * m31 - m30 * m21;
        const float det = s0 * c5 - s1 * c4_ + s2 * c3 + s3 * c2 - s4 * c1 + s5 * c0;
        const float id = 1.f / det;
        Inv[0][0] = ( m11 * c5 - m12 * c4_ + m13 * c3) * id;
        Inv[0][1] = (-m01 * c5 + m02 * c4_ - m03 * c3) * id;
        Inv[0][2] = ( m31 * s5 - m32 * s4 + m33 * s3) * id;
        Inv[0][3] = (-m21 * s5 + m22 * s4 - m23 * s3) * id;
        Inv[1][0] = (-m10 * c5 + m12 * c2 - m13 * c1) * id;
        Inv[1][1] = ( m00 * c5 - m02 * c2 + m03 * c1) * id;
        Inv[1][2] = (-m30 * s5 + m32 * s2 - m33 * s1) * id;
        Inv[1][3] = ( m20 * s5 - m22 * s2 + m23 * s1) * id;
        Inv[2][0] = ( m10 * c4_ - m11 * c2 + m13 * c0) * id;
        Inv[2][1] = (-m00 * c4_ + m01 * c2 - m03 * c0) * id;
        Inv[2][2] = ( m30 * s4 - m31 * s2 + m33 * s0) * id;
        Inv[2][3] = (-m20 * s4 + m21 * s2 - m23 * s0) * id;
        Inv[3][0] = (-m10 * c3 + m11 * c1 - m12 * c0) * id;
        Inv[3][1] = ( m00 * c3 - m01 * c1 + m02 * c0) * id;
        Inv[3][2] = (-m30 * s3 + m31 * s1 - m32 * s0) * id;
        Inv[3][3] = ( m20 * s3 - m21 * s1 + m22 * s0) * id;
    }
    float rxv[2], ryv[2], rzv[2], t0v[2], t1v[2], t2v[2];
#pragma unroll
    for (int v = 0; v < 2; ++v) {
        float M[3][4];
#pragma unroll
        for (int i = 0; i < 3; ++i)
#pragma unroll
            for (int j = 0; j < 4; ++j) {
                float acc = 0.f;
#pragma unroll
                for (int k = 0; k < 4; ++k) acc += P[v + 1][i][k] * Inv[k][j];
                M[i][j] = acc;
            }
        rxv[v] = fmaf(M[0][0], fx, fmaf(M[0][1], fy, M[0][2]));
        ryv[v] = fmaf(M[1][0], fx, fmaf(M[1][1], fy, M[1][2]));
        rzv[v] = fmaf(M[2][0], fx, fmaf(M[2][1], fy, M[2][2]));
        t0v[v] = M[0][3]; t1v[v] = M[1][3]; t2v[v] = M[2][3];
    }

    // ---------------- phase 1: stats (2 channels/lane) ---------------------
    int x0r[2], y0r[2];
    unsigned co[2][4];
    float mk[2][4];
#pragma unroll
    for (int v = 0; v < 2; ++v) {
        float pxn = fmaf(rxv[v], dep0, t0v[v]);
        float pyn = fmaf(ryv[v], dep0, t1v[v]);
        float z   = fmaf(rzv[v], dep0, t2v[v]);
        z = (fabsf(z) < 1e-6f) ? 1e-6f : z;
        float ri = frcp(z);
        float px = pxn * ri, py = pyn * ri;
        int x0 = (int)floorf(px), y0 = (int)floorf(py);
        x0r[v] = x0; y0r[v] = y0;
        bool vx0 = (x0 >= 0) && (x0 < NW);
        bool vx1 = (x0 + 1 >= 0) && (x0 + 1 < NW);
        bool vy0 = (y0 >= 0) && (y0 < NH);
        bool vy1 = (y0 + 1 >= 0) && (y0 + 1 < NH);
        mk[v][0] = (vx0 && vy0) ? 1.f : 0.f;
        mk[v][1] = (vx1 && vy0) ? 1.f : 0.f;
        mk[v][2] = (vx0 && vy1) ? 1.f : 0.f;
        mk[v][3] = (vx1 && vy1) ? 1.f : 0.f;
        int cx0 = min(max(x0, 0), NW - 1);
        int cx1 = min(max(x0 + 1, 0), NW - 1);
        int cy0 = min(max(y0, 0), NH - 1);
        int cy1 = min(max(y0 + 1, 0), NH - 1);
        co[v][0] = (unsigned)(cy0 * NW + cx0) * 4u;
        co[v][1] = (unsigned)(cy0 * NW + cx1) * 4u;
        co[v][2] = (unsigned)(cy1 * NW + cx0) * 4u;
        co[v][3] = (unsigned)(cy1 * NW + cx1) * 4u;
    }

    float G1[10], G2[10], Cm[16], R1[4], R2[4];
    float r2 = 0.f;
#pragma unroll
    for (int k = 0; k < 10; ++k) { G1[k] = 0.f; G2[k] = 0.f; }
#pragma unroll
    for (int k = 0; k < 16; ++k) Cm[k] = 0.f;
#pragma unroll
    for (int k = 0; k < 4; ++k) { R1[k] = 0.f; R2[k] = 0.f; }

#pragma unroll
    for (int c2 = 0; c2 < 2; ++c2) {
        const int c = r8 * 2 + c2;
        const char* f1c = f1b + (size_t)c * HW * 4;
        const char* f2c = f2b + (size_t)c * HW * 4;
        float r = rf[c2];
        float g1[4], g2[4];
#pragma unroll
        for (int i = 0; i < 4; ++i) {
            g1[i] = *(const float*)(f1c + co[0][i]) * mk[0][i];  // mask folded
            g2[i] = *(const float*)(f2c + co[1][i]) * mk[1][i];
        }
        float w = wreg[c];
        float wr = w * r;
        r2 = fmaf(wr, r, r2);
        float wg1[4], wg2[4];
#pragma unroll
        for (int i = 0; i < 4; ++i) { wg1[i] = w * g1[i]; wg2[i] = w * g2[i]; }
#pragma unroll
        for (int i = 0; i < 4; ++i) {
            R1[i] = fmaf(wr, g1[i], R1[i]);
            R2[i] = fmaf(wr, g2[i], R2[i]);
        }
#pragma unroll
        for (int i = 0; i < 4; ++i)
#pragma unroll
            for (int j = i; j < 4; ++j) {
                G1[SYM(i, j)] = fmaf(wg1[i], g1[j], G1[SYM(i, j)]);
                G2[SYM(i, j)] = fmaf(wg2[i], g2[j], G2[SYM(i, j)]);
            }
#pragma unroll
        for (int i = 0; i < 4; ++i)
#pragma unroll
            for (int j = 0; j < 4; ++j)
                Cm[i * 4 + j] = fmaf(wg1[i], g2[j], Cm[i * 4 + j]);
    }

    // 3-step butterfly allreduce across the 8-lane group
#pragma unroll
    for (int k = 0; k < 10; ++k) {
        G1[k] += __shfl_xor(G1[k], 1); G1[k] += __shfl_xor(G1[k], 2);
        G1[k] += __shfl_xor(G1[k], 4);
        G2[k] += __shfl_xor(G2[k], 1); G2[k] += __shfl_xor(G2[k], 2);
        G2[k] += __shfl_xor(G2[k], 4);
    }
#pragma unroll
    for (int k = 0; k < 16; ++k) {
        Cm[k] += __shfl_xor(Cm[k], 1); Cm[k] += __shfl_xor(Cm[k], 2);
        Cm[k] += __shfl_xor(Cm[k], 4);
    }
#pragma unroll
    for (int k = 0; k < 4; ++k) {
        R1[k] += __shfl_xor(R1[k], 1); R1[k] += __shfl_xor(R1[k], 2);
        R1[k] += __shfl_xor(R1[k], 4);
        R2[k] += __shfl_xor(R2[k], 1); R2[k] += __shfl_xor(R2[k], 2);
        R2[k] += __shfl_xor(R2[k], 4);
    }
    r2 += __shfl_xor(r2, 1); r2 += __shfl_xor(r2, 2); r2 += __shfl_xor(r2, 4);

    // double symmetric off-diagonals (R9 semantics: eval sums i<=j only)
#pragma unroll
    for (int i = 0; i < 4; ++i)
#pragma unroll
        for (int j = i + 1; j < 4; ++j) {
            G1[SYM(i, j)] += G1[SYM(i, j)];
            G2[SYM(i, j)] += G2[SYM(i, j)];
        }

    // ---------------- phase 2: eval 4 depths (quad-form direct) ------------
    float c[4];
    float mx = -INFINITY;
    {
        float pxs[2][4], pys[2][4];
#pragma unroll
        for (int dd = 0; dd < 4; ++dd) {
            const float depth = dv[dd];
#pragma unroll
            for (int v = 0; v < 2; ++v) {
                float pxn = fmaf(rxv[v], depth, t0v[v]);
                float pyn = fmaf(ryv[v], depth, t1v[v]);
                float z   = fmaf(rzv[v], depth, t2v[v]);
                z = (fabsf(z) < 1e-6f) ? 1e-6f : z;
                float ri = frcp(z);
                pxs[v][dd] = pxn * ri;
                pys[v][dd] = pyn * ri;
            }
        }
#pragma unroll
        for (int dd = 0; dd < 4; ++dd) {
            float wx[2], wy[2];
            int ax0[2], ay0[2];
            bool fast = true;
#pragma unroll
            for (int v = 0; v < 2; ++v) {
                float px = pxs[v][dd], py = pys[v][dd];
                float x0f = floorf(px), y0f = floorf(py);
                wx[v] = px - x0f;
                wy[v] = py - y0f;
                int x0 = (int)x0f, y0 = (int)y0f;
                ax0[v] = x0; ay0[v] = y0;
                fast = fast && (x0 == x0r[v]) && (y0 == y0r[v]);
            }

            float cst;
            if (fast) {
                // pure bilinear weights (masks live inside the sums)
                float al0[4], al1[4];
                {
                    float wxx = wx[0], wyy = wy[0];
                    al0[0] = (1.f - wxx) * (1.f - wyy);
                    al0[1] = wxx * (1.f - wyy);
                    al0[2] = (1.f - wxx) * wyy;
                    al0[3] = wxx * wyy;
                    wxx = wx[1]; wyy = wy[1];
                    al1[0] = (1.f - wxx) * (1.f - wyy);
                    al1[1] = wxx * (1.f - wyy);
                    al1[2] = (1.f - wxx) * wyy;
                    al1[3] = wxx * wyy;
                }
                float q1 = 0.f, q2 = 0.f;
#pragma unroll
                for (int i = 0; i < 4; ++i)
#pragma unroll
                    for (int j = i; j < 4; ++j) {
                        q1 = fmaf(G1[SYM(i, j)], al0[i] * al0[j], q1);
                        q2 = fmaf(G2[SYM(i, j)], al1[i] * al1[j], q2);
                    }
                float qc = 0.f;
#pragma unroll
                for (int i = 0; i < 4; ++i)
#pragma unroll
                    for (int j = 0; j < 4; ++j)
                        qc = fmaf(Cm[i * 4 + j], al0[i] * al1[j], qc);
                float lr = 0.f;
#pragma unroll
                for (int i = 0; i < 4; ++i) {
                    lr = fmaf(R1[i], al0[i], lr);
                    lr = fmaf(R2[i], al1[i], lr);
                }
                cst = (2.f / 9.f) * (r2 + q1 + q2 - lr - qc);
            } else {
                // slow path: exact direct regather with full mask logic
                float al[2][4];
                unsigned so[2][4];
#pragma unroll
                for (int v = 0; v < 2; ++v) {
                    int x0 = ax0[v], y0 = ay0[v];
                    bool vx0 = (x0 >= 0) && (x0 < NW);
                    bool vx1 = (x0 + 1 >= 0) && (x0 + 1 < NW);
                    bool vy0 = (y0 >= 0) && (y0 < NH);
                    bool vy1 = (y0 + 1 >= 0) && (y0 + 1 < NH);
                    float wxx = wx[v], wyy = wy[v];
                    al[v][0] = (1.f - wxx) * (1.f - wyy) * ((vx0 && vy0) ? 1.f : 0.f);
                    al[v][1] = wxx * (1.f - wyy) * ((vx1 && vy0) ? 1.f : 0.f);
                    al[v][2] = (1.f - wxx) * wyy * ((vx0 && vy1) ? 1.f : 0.f);
                    al[v][3] = wxx * wyy * ((vx1 && vy1) ? 1.f : 0.f);
                    int cx0 = min(max(x0, 0), NW - 1);
                    int cx1 = min(max(x0 + 1, 0), NW - 1);
                    int cy0 = min(max(y0, 0), NH - 1);
                    int cy1 = min(max(y0 + 1, 0), NH - 1);
                    so[v][0] = (unsigned)(cy0 * NW + cx0) * 4u;
                    so[v][1] = (unsigned)(cy0 * NW + cx1) * 4u;
                    so[v][2] = (unsigned)(cy1 * NW + cx0) * 4u;
                    so[v][3] = (unsigned)(cy1 * NW + cx1) * 4u;
                }
                float acc = 0.f;
#pragma unroll
                for (int cc = 0; cc < NC; ++cc) {
                    const char* frc = fb + (size_t)cc * HW * 4;
                    const char* f1c = f1b + (size_t)cc * HW * 4;
                    const char* f2c = f2b + (size_t)cc * HW * 4;
                    float r = *(const float*)(frc + voff);
                    float s1 = 0.f, s2 = 0.f;
#pragma unroll
                    for (int i = 0; i < 4; ++i) {
                        s1 = fmaf(*(const float*)(f1c + so[0][i]), al[0][i], s1);
                        s2 = fmaf(*(const float*)(f2c + so[1][i]), al[1][i], s2);
                    }
                    float e = r * r + s1 * s1 + s2 * s2
                            - r * s1 - r * s2 - s1 * s2;
                    acc = fmaf(wreg[cc], e, acc);
                }
                cst = (2.f / 9.f) * acc;
            }
            c[dd] = cst;
            mx = fmaxf(mx, cst);
        }
    }

    // cross-lane softmax over the 8-lane group
    mx = fmaxf(mx, __shfl_xor(mx, 1));
    mx = fmaxf(mx, __shfl_xor(mx, 2));
    mx = fmaxf(mx, __shfl_xor(mx, 4));
    float ssum = 0.f;
#pragma unroll
    for (int i = 0; i < 4; ++i) {
        float e = __expf(c[i] - mx);
        c[i] = e;
        ssum += e;
    }
    ssum += __shfl_xor(ssum, 1);
    ssum += __shfl_xor(ssum, 2);
    ssum += __shfl_xor(ssum, 4);
    float inv = 1.f / ssum;

    float* prob = out + 2 * HW;
    float depth_acc = 0.f, didx_acc = 0.f;
#pragma unroll
    for (int i = 0; i < 4; ++i) {
        float pv = c[i] * inv;
        c[i] = pv;
        *(float*)((char*)prob + (size_t)(d0 + i) * HW * 4 + voff) = pv;
        depth_acc = fmaf(pv, dv[i], depth_acc);
        didx_acc = fmaf(pv, (float)(d0 + i), didx_acc);
    }
    depth_acc += __shfl_xor(depth_acc, 1);
    depth_acc += __shfl_xor(depth_acc, 2);
    depth_acc += __shfl_xor(depth_acc, 4);
    didx_acc += __shfl_xor(didx_acc, 1);
    didx_acc += __shfl_xor(didx_acc, 2);
    didx_acc += __shfl_xor(didx_acc, 4);

    int di = (int)didx_acc;            // trunc toward zero == astype(int32)
    di = min(max(di, 0), ND - 1);
    float pdi = 0.f, pdi1 = 0.f;
#pragma unroll
    for (int i = 0; i < 4; ++i) {
        pdi  = (d0 + i == di)     ? c[i] : pdi;
        pdi1 = (d0 + i == di + 1) ? c[i] : pdi1;
    }
    pdi  += __shfl_xor(pdi, 1);
    pdi  += __shfl_xor(pdi, 2);
    pdi  += __shfl_xor(pdi, 4);
    pdi1 += __shfl_xor(pdi1, 1);
    pdi1 += __shfl_xor(pdi1, 2);
    pdi1 += __shfl_xor(pdi1, 4);

    if (r8 == 0) {
        out[n] = depth_acc;
        out[HW + n] = pdi + pdi1;
    }
}

extern "C" void kernel_launch(void* const* d_in, const int* in_sizes, int n_in,
                              void* d_out, int out_size, void* d_ws, size_t ws_size,
                              hipStream_t stream) {
    const float* feats = (const float*)d_in[0];
    const float* pm    = (const float*)d_in[1];
    const float* dvals = (const float*)d_in[2];
    const float* wreg  = (const float*)d_in[3];
    float* out = (float*)d_out;
    (void)d_ws; (void)ws_size;

    mega4_kernel<<<HW * 8 / 256, 256, 0, stream>>>(feats, pm, dvals, wreg,
                                                   out);
}

// Round 18
// 26.372 us; speedup vs baseline: 1.5461x; 1.5461x over previous
//
#include <hip/hip_runtime.h>
#include <math.h>

namespace {
constexpr int NV = 3;    // views
constexpr int NC = 16;   // channels
constexpr int ND = 32;   // depths
constexpr int NH = 256;
constexpr int NW = 320;
constexpr int HW = NH * NW;       // 81920
#define SYM(i, j) ((i) * 4 + (j) - (i) * ((i) + 1) / 2)
}

// rcp + 1 Newton step (same sequence everywhere -> consistent anchors).
__device__ __forceinline__ float frcp(float z) {
    float r = __builtin_amdgcn_rcpf(z);
    return r * fmaf(-z, r, 2.0f);
}

// ---------------------------------------------------------------------------
// R18 = R16 verbatim (best: 26.5 us). Structure ledger (all refuted):
//  R5/R6 ILP load-batching, R3/R8/R11 per-thread amplification, R10/R13
//  memory round-trips, R15 setup split, R17 TLP x2 (counters: work grew
//  faster than latency hiding). R16 = single kernel, 4 lanes/pixel,
//  register handoff stats->eval, early-load hoist, __expf.
// ---------------------------------------------------------------------------
__global__ __launch_bounds__(256) void mega3_kernel(
    const float* __restrict__ feats,   // [V][C][HW]
    const float* __restrict__ pm,      // [V][2][4][4]
    const float* __restrict__ dvals,   // [D][HW]
    const float* __restrict__ wreg,    // [C]
    float* __restrict__ out)           // depth[HW] | conf[HW] | prob[D][HW]
{
    const unsigned tid = blockIdx.x * 256u + threadIdx.x;
    const unsigned n = tid >> 2;       // pixel
    const int q = (int)(tid & 3u);     // lane-in-group: channel & depth quarter
    const int d0 = q * 8;
    const int y = (int)(n / NW);
    const int x = (int)(n - (unsigned)y * NW);
    const float fx = (float)x, fy = (float)y;
    const unsigned voff = n * 4u;

    const char* fb = (const char*)feats;
    const char* f1b = fb + (size_t)1 * NC * HW * 4;
    const char* f2b = fb + (size_t)2 * NC * HW * 4;

    // ------- EARLY LOADS: addresses depend only on (n, q); issue before the
    // uniform proj math so latency hides under it -------------------------
    const float dep0 = *(const float*)((const char*)dvals + voff);
    float rf[4];
#pragma unroll
    for (int c4 = 0; c4 < 4; ++c4)
        rf[c4] = *(const float*)(fb + (size_t)(q * 4 + c4) * HW * 4 + voff);
    float dv[8];
#pragma unroll
    for (int i = 0; i < 8; ++i)
        dv[i] = *(const float*)((const char*)dvals +
                                (size_t)(d0 + i) * HW * 4 + voff);

    // ---------------- phase 0: projection matrices (uniform math) ----------
    float P[NV][4][4];
#pragma unroll
    for (int v = 0; v < NV; ++v) {
        const float* E = pm + v * 2 * 16;
        const float* K = pm + v * 2 * 16 + 16;
#pragma unroll
        for (int j = 0; j < 4; ++j) P[v][3][j] = E[12 + j];
#pragma unroll
        for (int i = 0; i < 3; ++i)
#pragma unroll
            for (int j = 0; j < 4; ++j) {
                float acc = 0.f;
#pragma unroll
                for (int k = 0; k < 3; ++k) acc += K[i * 4 + k] * E[k * 4 + j];
                P[v][i][j] = acc;
            }
    }
    float Inv[4][4];
    {
        const float m00 = P[0][0][0], m01 = P[0][0][1], m02 = P[0][0][2], m03 = P[0][0][3];
        const float m10 = P[0][1][0], m11 = P[0][1][1], m12 = P[0][1][2], m13 = P[0][1][3];
        const float m20 = P[0][2][0], m21 = P[0][2][1], m22 = P[0][2][2], m23 = P[0][2][3];
        const float m30 = P[0][3][0], m31 = P[0][3][1], m32 = P[0][3][2], m33 = P[0][3][3];
        const float s0 = m00 * m11 - m10 * m01;
        const float s1 = m00 * m12 - m10 * m02;
        const float s2 = m00 * m13 - m10 * m03;
        const float s3 = m01 * m12 - m11 * m02;
        const float s4 = m01 * m13 - m11 * m03;
        const float s5 = m02 * m13 - m12 * m03;
        const float c5 = m22 * m33 - m32 * m23;
        const float c4_ = m21 * m33 - m31 * m23;
        const float c3 = m21 * m32 - m31 * m22;
        const float c2 = m20 * m33 - m30 * m23;
        const float c1 = m20 * m32 - m30 * m22;
        const float c0 = m20 * m31 - m30 * m21;
        const float det = s0 * c5 - s1 * c4_ + s2 * c3 + s3 * c2 - s4 * c1 + s5 * c0;
        const float id = 1.f / det;
        Inv[0][0] = ( m11 * c5 - m12 * c4_ + m13 * c3) * id;
        Inv[0][1] = (-m01 * c5 + m02 * c4_ - m03 * c3) * id;
        Inv[0][2] = ( m31 * s5 - m32 * s4 + m33 * s3) * id;
        Inv[0][3] = (-m21 * s5 + m22 * s4 - m23 * s3) * id;
        Inv[1][0] = (-m10 * c5 + m12 * c2 - m13 * c1) * id;
        Inv[1][1] = ( m00 * c5 - m02 * c2 + m03 * c1) * id;
        Inv[1][2] = (-m30 * s5 + m32 * s2 - m33 * s1) * id;
        Inv[1][3] = ( m20 * s5 - m22 * s2 + m23 * s1) * id;
        Inv[2][0] = ( m10 * c4_ - m11 * c2 + m13 * c0) * id;
        Inv[2][1] = (-m00 * c4_ + m01 * c2 - m03 * c0) * id;
        Inv[2][2] = ( m30 * s4 - m31 * s2 + m33 * s0) * id;
        Inv[2][3] = (-m20 * s4 + m21 * s2 - m23 * s0) * id;
        Inv[3][0] = (-m10 * c3 + m11 * c1 - m12 * c0) * id;
        Inv[3][1] = ( m00 * c3 - m01 * c1 + m02 * c0) * id;
        Inv[3][2] = (-m30 * s3 + m31 * s1 - m32 * s0) * id;
        Inv[3][3] = ( m20 * s3 - m21 * s1 + m22 * s0) * id;
    }
    float rxv[2], ryv[2], rzv[2], t0v[2], t1v[2], t2v[2];
#pragma unroll
    for (int v = 0; v < 2; ++v) {
        float M[3][4];
#pragma unroll
        for (int i = 0; i < 3; ++i)
#pragma unroll
            for (int j = 0; j < 4; ++j) {
                float acc = 0.f;
#pragma unroll
                for (int k = 0; k < 4; ++k) acc += P[v + 1][i][k] * Inv[k][j];
                M[i][j] = acc;
            }
        rxv[v] = fmaf(M[0][0], fx, fmaf(M[0][1], fy, M[0][2]));
        ryv[v] = fmaf(M[1][0], fx, fmaf(M[1][1], fy, M[1][2]));
        rzv[v] = fmaf(M[2][0], fx, fmaf(M[2][1], fy, M[2][2]));
        t0v[v] = M[0][3]; t1v[v] = M[1][3]; t2v[v] = M[2][3];
    }

    // ---------------- phase 1: stats -> polynomial coefficients ------------
    int x0r[2], y0r[2];
    unsigned co[2][4];
    float mk[2][4];
#pragma unroll
    for (int v = 0; v < 2; ++v) {
        float pxn = fmaf(rxv[v], dep0, t0v[v]);
        float pyn = fmaf(ryv[v], dep0, t1v[v]);
        float z   = fmaf(rzv[v], dep0, t2v[v]);
        z = (fabsf(z) < 1e-6f) ? 1e-6f : z;
        float ri = frcp(z);
        float px = pxn * ri, py = pyn * ri;
        int x0 = (int)floorf(px), y0 = (int)floorf(py);
        x0r[v] = x0; y0r[v] = y0;
        bool vx0 = (x0 >= 0) && (x0 < NW);
        bool vx1 = (x0 + 1 >= 0) && (x0 + 1 < NW);
        bool vy0 = (y0 >= 0) && (y0 < NH);
        bool vy1 = (y0 + 1 >= 0) && (y0 + 1 < NH);
        mk[v][0] = (vx0 && vy0) ? 1.f : 0.f;
        mk[v][1] = (vx1 && vy0) ? 1.f : 0.f;
        mk[v][2] = (vx0 && vy1) ? 1.f : 0.f;
        mk[v][3] = (vx1 && vy1) ? 1.f : 0.f;
        int cx0 = min(max(x0, 0), NW - 1);
        int cx1 = min(max(x0 + 1, 0), NW - 1);
        int cy0 = min(max(y0, 0), NH - 1);
        int cy1 = min(max(y0 + 1, 0), NH - 1);
        co[v][0] = (unsigned)(cy0 * NW + cx0) * 4u;
        co[v][1] = (unsigned)(cy0 * NW + cx1) * 4u;
        co[v][2] = (unsigned)(cy1 * NW + cx0) * 4u;
        co[v][3] = (unsigned)(cy1 * NW + cx1) * 4u;
    }

    float G1[10], G2[10], Cm[16], R1[4], R2[4];
    float r2 = 0.f;
#pragma unroll
    for (int k = 0; k < 10; ++k) { G1[k] = 0.f; G2[k] = 0.f; }
#pragma unroll
    for (int k = 0; k < 16; ++k) Cm[k] = 0.f;
#pragma unroll
    for (int k = 0; k < 4; ++k) { R1[k] = 0.f; R2[k] = 0.f; }

#pragma unroll
    for (int c4 = 0; c4 < 4; ++c4) {
        const int c = q * 4 + c4;
        const char* f1c = f1b + (size_t)c * HW * 4;
        const char* f2c = f2b + (size_t)c * HW * 4;
        float r = rf[c4];
        float g1[4], g2[4];
#pragma unroll
        for (int i = 0; i < 4; ++i) {
            g1[i] = *(const float*)(f1c + co[0][i]) * mk[0][i];  // mask folded
            g2[i] = *(const float*)(f2c + co[1][i]) * mk[1][i];
        }
        float w = wreg[c];
        float wr = w * r;
        r2 = fmaf(wr, r, r2);
        float wg1[4], wg2[4];
#pragma unroll
        for (int i = 0; i < 4; ++i) { wg1[i] = w * g1[i]; wg2[i] = w * g2[i]; }
#pragma unroll
        for (int i = 0; i < 4; ++i) {
            R1[i] = fmaf(wr, g1[i], R1[i]);
            R2[i] = fmaf(wr, g2[i], R2[i]);
        }
#pragma unroll
        for (int i = 0; i < 4; ++i)
#pragma unroll
            for (int j = i; j < 4; ++j) {
                G1[SYM(i, j)] = fmaf(wg1[i], g1[j], G1[SYM(i, j)]);
                G2[SYM(i, j)] = fmaf(wg2[i], g2[j], G2[SYM(i, j)]);
            }
#pragma unroll
        for (int i = 0; i < 4; ++i)
#pragma unroll
            for (int j = 0; j < 4; ++j)
                Cm[i * 4 + j] = fmaf(wg1[i], g2[j], Cm[i * 4 + j]);
    }

    // butterfly allreduce: after this every lane holds the full 45 sums
#pragma unroll
    for (int k = 0; k < 10; ++k) {
        G1[k] += __shfl_xor(G1[k], 1); G1[k] += __shfl_xor(G1[k], 2);
        G2[k] += __shfl_xor(G2[k], 1); G2[k] += __shfl_xor(G2[k], 2);
    }
#pragma unroll
    for (int k = 0; k < 16; ++k) {
        Cm[k] += __shfl_xor(Cm[k], 1); Cm[k] += __shfl_xor(Cm[k], 2);
    }
#pragma unroll
    for (int k = 0; k < 4; ++k) {
        R1[k] += __shfl_xor(R1[k], 1); R1[k] += __shfl_xor(R1[k], 2);
        R2[k] += __shfl_xor(R2[k], 1); R2[k] += __shfl_xor(R2[k], 2);
    }
    r2 += __shfl_xor(r2, 1); r2 += __shfl_xor(r2, 2);

    // basis change: quad-form -> polynomial coefficients (in registers)
    static constexpr float U2[3][3] = {{1.f,-2.f,1.f},{0.f,1.f,-1.f},{0.f,0.f,1.f}};
    static constexpr float U1[2][2] = {{1.f,-1.f},{0.f,1.f}};
    float A[9], Bp[9], Xc[16];
#pragma unroll
    for (int k = 0; k < 9; ++k) { A[k] = 0.f; Bp[k] = 0.f; }
#pragma unroll
    for (int k = 0; k < 16; ++k) Xc[k] = 0.f;
    A[0] = r2;
#pragma unroll
    for (int i = 0; i < 4; ++i) {
#pragma unroll
        for (int j = 0; j < 4; ++j) {
            const int lo = i < j ? i : j, hi = i < j ? j : i;
            const float g1v = G1[SYM(lo, hi)];
            const float g2v = G2[SYM(lo, hi)];
            const int m = i & 1, kk = i >> 1, nn = j & 1, ll = j >> 1;
#pragma unroll
            for (int p = 0; p < 3; ++p)
#pragma unroll
                for (int qq = 0; qq < 3; ++qq) {
                    const float cc = U2[m + nn][p] * U2[kk + ll][qq];
                    if (cc != 0.f) {
                        A[p * 3 + qq] += g1v * cc;
                        Bp[p * 3 + qq] += g2v * cc;
                    }
                }
        }
    }
#pragma unroll
    for (int i = 0; i < 4; ++i) {
        const int m = i & 1, kk = i >> 1;
#pragma unroll
        for (int p = 0; p < 2; ++p)
#pragma unroll
            for (int qq = 0; qq < 2; ++qq) {
                const float cc = U1[m][p] * U1[kk][qq];
                if (cc != 0.f) {
                    A[p * 3 + qq] -= R1[i] * cc;
                    Bp[p * 3 + qq] -= R2[i] * cc;
                }
            }
    }
#pragma unroll
    for (int i = 0; i < 4; ++i) {
        const int m = i & 1, kk = i >> 1;
#pragma unroll
        for (int j = 0; j < 4; ++j) {
            const int nn = j & 1, ll = j >> 1;
            const float cv = Cm[i * 4 + j];
#pragma unroll
            for (int p = 0; p < 2; ++p)
#pragma unroll
                for (int qq = 0; qq < 2; ++qq)
#pragma unroll
                    for (int rr = 0; rr < 2; ++rr)
#pragma unroll
                        for (int ss = 0; ss < 2; ++ss) {
                            const float cc = U1[m][p] * U1[kk][qq]
                                           * U1[nn][rr] * U1[ll][ss];
                            if (cc != 0.f)
                                Xc[p * 8 + qq * 4 + rr * 2 + ss] -= cv * cc;
                        }
        }
    }

    // ---------------- phase 2: eval 8 depths + softmax ---------------------
    float c[8];
    float mx = -INFINITY;
#pragma unroll
    for (int ck = 0; ck < 2; ++ck) {
        float pxs[2][4], pys[2][4];
#pragma unroll
        for (int dd = 0; dd < 4; ++dd) {
            const float depth = dv[ck * 4 + dd];
#pragma unroll
            for (int v = 0; v < 2; ++v) {
                float pxn = fmaf(rxv[v], depth, t0v[v]);
                float pyn = fmaf(ryv[v], depth, t1v[v]);
                float z   = fmaf(rzv[v], depth, t2v[v]);
                z = (fabsf(z) < 1e-6f) ? 1e-6f : z;
                float ri = frcp(z);
                pxs[v][dd] = pxn * ri;
                pys[v][dd] = pyn * ri;
            }
        }
#pragma unroll
        for (int dd = 0; dd < 4; ++dd) {
            float wx[2], wy[2];
            int ax0[2], ay0[2];
            bool fast = true;
#pragma unroll
            for (int v = 0; v < 2; ++v) {
                float px = pxs[v][dd], py = pys[v][dd];
                float x0f = floorf(px), y0f = floorf(py);
                wx[v] = px - x0f;
                wy[v] = py - y0f;
                int x0 = (int)x0f, y0 = (int)y0f;
                ax0[v] = x0; ay0[v] = y0;
                fast = fast && (x0 == x0r[v]) && (y0 == y0r[v]);
            }

            float cst;
            if (fast) {
                const float wx0 = wx[0], wy0 = wy[0];
                const float wx1 = wx[1], wy1 = wy[1];
                float a0 = fmaf(wy0, fmaf(wy0, A[2], A[1]), A[0]);
                float a1 = fmaf(wy0, fmaf(wy0, A[5], A[4]), A[3]);
                float a2 = fmaf(wy0, fmaf(wy0, A[8], A[7]), A[6]);
                float PA = fmaf(wx0, fmaf(wx0, a2, a1), a0);
                float b0 = fmaf(wy1, fmaf(wy1, Bp[2], Bp[1]), Bp[0]);
                float b1 = fmaf(wy1, fmaf(wy1, Bp[5], Bp[4]), Bp[3]);
                float b2 = fmaf(wy1, fmaf(wy1, Bp[8], Bp[7]), Bp[6]);
                float PB = fmaf(wx1, fmaf(wx1, b2, b1), b0);
                float y0_ = fmaf(wy1, Xc[1], Xc[0]);
                float y1_ = fmaf(wy1, Xc[3], Xc[2]);
                float y2_ = fmaf(wy1, Xc[5], Xc[4]);
                float y3_ = fmaf(wy1, Xc[7], Xc[6]);
                float y4_ = fmaf(wy1, Xc[9], Xc[8]);
                float y5_ = fmaf(wy1, Xc[11], Xc[10]);
                float y6_ = fmaf(wy1, Xc[13], Xc[12]);
                float y7_ = fmaf(wy1, Xc[15], Xc[14]);
                float z0_ = fmaf(wx1, y1_, y0_);
                float z1_ = fmaf(wx1, y3_, y2_);
                float z2_ = fmaf(wx1, y5_, y4_);
                float z3_ = fmaf(wx1, y7_, y6_);
                float w0_ = fmaf(wy0, z1_, z0_);
                float w1_ = fmaf(wy0, z3_, z2_);
                float Xv = fmaf(wx0, w1_, w0_);
                cst = (2.f / 9.f) * (PA + PB + Xv);
            } else {
                // slow path: exact direct regather with full mask logic
                float al[2][4];
                unsigned so[2][4];
#pragma unroll
                for (int v = 0; v < 2; ++v) {
                    int x0 = ax0[v], y0 = ay0[v];
                    bool vx0 = (x0 >= 0) && (x0 < NW);
                    bool vx1 = (x0 + 1 >= 0) && (x0 + 1 < NW);
                    bool vy0 = (y0 >= 0) && (y0 < NH);
                    bool vy1 = (y0 + 1 >= 0) && (y0 + 1 < NH);
                    float wxx = wx[v], wyy = wy[v];
                    al[v][0] = (1.f - wxx) * (1.f - wyy) * ((vx0 && vy0) ? 1.f : 0.f);
                    al[v][1] = wxx * (1.f - wyy) * ((vx1 && vy0) ? 1.f : 0.f);
                    al[v][2] = (1.f - wxx) * wyy * ((vx0 && vy1) ? 1.f : 0.f);
                    al[v][3] = wxx * wyy * ((vx1 && vy1) ? 1.f : 0.f);
                    int cx0 = min(max(x0, 0), NW - 1);
                    int cx1 = min(max(x0 + 1, 0), NW - 1);
                    int cy0 = min(max(y0, 0), NH - 1);
                    int cy1 = min(max(y0 + 1, 0), NH - 1);
                    so[v][0] = (unsigned)(cy0 * NW + cx0) * 4u;
                    so[v][1] = (unsigned)(cy0 * NW + cx1) * 4u;
                    so[v][2] = (unsigned)(cy1 * NW + cx0) * 4u;
                    so[v][3] = (unsigned)(cy1 * NW + cx1) * 4u;
                }
                float acc = 0.f;
#pragma unroll
                for (int cc = 0; cc < NC; ++cc) {
                    const char* frc = fb + (size_t)cc * HW * 4;
                    const char* f1c = f1b + (size_t)cc * HW * 4;
                    const char* f2c = f2b + (size_t)cc * HW * 4;
                    float r = *(const float*)(frc + voff);
                    float s1 = 0.f, s2 = 0.f;
#pragma unroll
                    for (int i = 0; i < 4; ++i) {
                        s1 = fmaf(*(const float*)(f1c + so[0][i]), al[0][i], s1);
                        s2 = fmaf(*(const float*)(f2c + so[1][i]), al[1][i], s2);
                    }
                    float e = r * r + s1 * s1 + s2 * s2
                            - r * s1 - r * s2 - s1 * s2;
                    acc = fmaf(wreg[cc], e, acc);
                }
                cst = (2.f / 9.f) * acc;
            }
            c[ck * 4 + dd] = cst;
            mx = fmaxf(mx, cst);
        }
    }

    // cross-lane softmax over the 4-lane group
    mx = fmaxf(mx, __shfl_xor(mx, 1));
    mx = fmaxf(mx, __shfl_xor(mx, 2));
    float ssum = 0.f;
#pragma unroll
    for (int i = 0; i < 8; ++i) {
        float e = __expf(c[i] - mx);
        c[i] = e;
        ssum += e;
    }
    ssum += __shfl_xor(ssum, 1);
    ssum += __shfl_xor(ssum, 2);
    float inv = 1.f / ssum;

    float* prob = out + 2 * HW;
    float depth_acc = 0.f, didx_acc = 0.f;
#pragma unroll
    for (int i = 0; i < 8; ++i) {
        float pv = c[i] * inv;
        c[i] = pv;
        *(float*)((char*)prob + (size_t)(d0 + i) * HW * 4 + voff) = pv;
        depth_acc = fmaf(pv, dv[i], depth_acc);
        didx_acc = fmaf(pv, (float)(d0 + i), didx_acc);
    }
    depth_acc += __shfl_xor(depth_acc, 1);
    depth_acc += __shfl_xor(depth_acc, 2);
    didx_acc += __shfl_xor(didx_acc, 1);
    didx_acc += __shfl_xor(didx_acc, 2);

    int di = (int)didx_acc;            // trunc toward zero == astype(int32)
    di = min(max(di, 0), ND - 1);
    float pdi = 0.f, pdi1 = 0.f;
#pragma unroll
    for (int i = 0; i < 8; ++i) {
        pdi  = (d0 + i == di)     ? c[i] : pdi;
        pdi1 = (d0 + i == di + 1) ? c[i] : pdi1;
    }
    pdi  += __shfl_xor(pdi, 1);
    pdi  += __shfl_xor(pdi, 2);
    pdi1 += __shfl_xor(pdi1, 1);
    pdi1 += __shfl_xor(pdi1, 2);

    if (q == 0) {
        out[n] = depth_acc;
        out[HW + n] = pdi + pdi1;
    }
}

extern "C" void kernel_launch(void* const* d_in, const int* in_sizes, int n_in,
                              void* d_out, int out_size, void* d_ws, size_t ws_size,
                              hipStream_t stream) {
    const float* feats = (const float*)d_in[0];
    const float* pm    = (const float*)d_in[1];
    const float* dvals = (const float*)d_in[2];
    const float* wreg  = (const float*)d_in[3];
    float* out = (float*)d_out;
    (void)d_ws; (void)ws_size;

    mega3_kernel<<<HW * 4 / 256, 256, 0, stream>>>(feats, pm, dvals, wreg,
                                                   out);
}